// Round 4
// baseline (154.941 us; speedup 1.0000x reference)
//
#include <hip/hip_runtime.h>
#include <hip/hip_bf16.h>
#include <stdint.h>
#include <math.h>

#define B_ 16
#define T_ 512
#define V_ 16
#define H_ 128
#define NC_ 12

typedef float v2f __attribute__((ext_vector_type(2)));
typedef __attribute__((ext_vector_type(8))) short s8frag;   // 8 bf16 (4 VGPRs)
typedef __attribute__((ext_vector_type(4))) float f4frag;   // 4 fp32 acc
typedef unsigned long long u64;

// ws layout: feat[B_*H_] at offset 0 (8 KB)

__global__ __launch_bounds__(1024) void zero_feat_kernel(float* __restrict__ feat) {
    int i = blockIdx.x * 1024 + threadIdx.x;
    if (i < B_ * H_) feat[i] = 0.f;
}

// Block = 1024 threads = 16 waves. blockIdx = b*64 + chunk; block covers 128
// sites (2 groups of 64). Per group: phase1 computes per-site step-spike masks
// (exact LIF1 via nested trajectory ballots), phase1.5 expands masks into bf16
// MFMA A-fragments (LDS LUT), phase2 runs split-bf16 MFMA (B register-resident
// per wave: wave owns N-slice of 16 output channels) + BN2/LIF2 epilogue.
__global__ __launch_bounds__(1024, 4) void snn_main(
    const float* __restrict__ x,
    const float* __restrict__ w1, const float* __restrict__ b1,
    const float* __restrict__ g1, const float* __restrict__ be1,
    const float* __restrict__ m1, const float* __restrict__ rv1,
    const float* __restrict__ w2, const float* __restrict__ b2,
    const float* __restrict__ g2, const float* __restrict__ be2,
    const float* __restrict__ m2, const float* __restrict__ rv2,
    float* __restrict__ feat)
{
    __shared__ union {
        unsigned short Bw[2 * H_ * H_];   // phase0: w2 split bf16 (hi | lo), 64 KB
        uint4 afrag[16 * 4 * 64];         // groups: A-frags [tile][chunk][lane], 64 KB
    } u;
    __shared__ u64 mask_lds[64 * 8];      // [site_local*8 + step*2 + half]
    __shared__ u64 lut[16];               // nibble -> 4 bf16 {0,1}
    __shared__ float red[8 * 16];

    const int tid  = threadIdx.x;
    const int lane = tid & 63;
    const int wave = tid >> 6;            // 0..15
    const int b     = blockIdx.x >> 6;
    const int chunk = blockIdx.x & 63;
    const int slice = wave & 7;           // N-slice: channels slice*16..+15
    const int kg    = lane >> 4;          // k-quad within fragment

    // ---- phase 0a: bit->bf16 LUT ----
    if (tid < 16) {
        u64 v = 0;
        #pragma unroll
        for (int j = 0; j < 4; ++j)
            if ((tid >> j) & 1) v |= (u64)0x3F80u << (16 * j);
        lut[tid] = v;
    }

    // ---- phase 0b: build split-bf16 B in LDS: B[k=o][n=p] = w2[p][o] stored [p*128+o] ----
    for (int i = tid; i < H_ * H_; i += 1024) {
        float w = w2[i];
        __hip_bfloat16 hb = __float2bfloat16(w);
        float hf = __bfloat162float(hb);
        __hip_bfloat16 lb = __float2bfloat16(w - hf);
        u.Bw[i]            = *(unsigned short*)&hb;
        u.Bw[H_ * H_ + i]  = *(unsigned short*)&lb;
    }

    // ---- per-lane constants (fc1/BN1 for channel pair, BN2 for epilogue channel) ----
    const int p = lane, q = lane + 64;
    v2f w0v = { w1[p*3+0], w1[q*3+0] };
    v2f w1v = { w1[p*3+1], w1[q*3+1] };
    v2f w2v = { w1[p*3+2], w1[q*3+2] };
    v2f b1v = { b1[p], b1[q] };
    float i1a = g1[p] * (float)(1.0 / sqrt((double)(rv1[p] + 1e-5f)));
    float i1b = g1[q] * (float)(1.0 / sqrt((double)(rv1[q] + 1e-5f)));
    v2f i1v = { i1a, i1b };
    v2f d1v = { be1[p] - m1[p] * i1a, be1[q] - m1[q] * i1b };
    const int ch = slice * 16 + (lane & 15);          // epilogue output channel
    float i2c = g2[ch] * (float)(1.0 / sqrt((double)(rv2[ch] + 1e-5f)));
    float d2c = be2[ch] - m2[ch] * i2c;
    float b2c = b2[ch];

    __syncthreads();

    // ---- phase 0c: load register-resident B fragments (wave's N-slice, all K) ----
    s8frag bhi[4], blo[4];
    #pragma unroll
    for (int c = 0; c < 4; ++c) {
        int idx = ch * H_ + c * 32 + kg * 8;          // [n][k] row-major = [p*128+o]
        bhi[c] = *(const s8frag*)&u.Bw[idx];
        blo[c] = *(const s8frag*)&u.Bw[H_ * H_ + idx];
    }
    __syncthreads();   // Bw consumed; afrag may overwrite

    float facc = 0.f;
    const int tile_own = wave;             // afrag build assignment
    const int tbase = (wave >> 3) * 8;     // phase2: waves 0-7 tiles 0-7, 8-15 tiles 8-15

    for (int g = 0; g < 2; ++g) {
        // ---- phase 1: LIF1 step-spike masks for 4 sites per wave ----
        #pragma unroll
        for (int i = 0; i < 4; ++i) {
            int sl   = wave + 16 * i;                 // site_local 0..63
            int site = chunk * 128 + g * 64 + sl;     // within batch b
            int t = site >> 4, v = site & 15;
            const float* xp = x + ((size_t)(b * T_ + t) * 3) * V_ + v;
            float x0 = xp[0], x1 = xp[V_], x2 = xp[2 * V_];   // wave-uniform

            v2f h1 = ((x0 * w0v + x1 * w1v + x2 * w2v) + b1v) * i1v + d1v;
            // unreset trajectory (exact reference rounding; monotone for crossers)
            v2f v1t = h1 * 0.5f;
            v2f v2t = v1t + h1 * 0.25f;
            v2f v3t = v2t + (h1 - v2t) * 0.5f;
            v2f v4t = v3t + (h1 - v3t) * 0.5f;

            u64 t1a = __ballot(v1t.x >= 0.5f), t2a = __ballot(v2t.x >= 0.5f);
            u64 t3a = __ballot(v3t.x >= 0.5f), t4a = __ballot(v4t.x >= 0.5f);
            u64 t1b = __ballot(v1t.y >= 0.5f), t2b = __ballot(v2t.y >= 0.5f);
            u64 t3b = __ballot(v3t.y >= 0.5f), t4b = __ballot(v4t.y >= 0.5f);
            // step-spike masks: s1=t1, s2=t2, s3=t1|(t3&~t2), s4=t2|(t4&~t3)
            u64 s3a = t1a | (t3a & ~t2a), s3b = t1b | (t3b & ~t2b);
            u64 s4a = t2a | (t4a & ~t3a), s4b = t2b | (t4b & ~t3b);

            if (lane < 8) {
                int stp = lane >> 1; bool hf = lane & 1;
                u64 vm;
                if      (stp == 0) vm = hf ? t1b : t1a;
                else if (stp == 1) vm = hf ? t2b : t2a;
                else if (stp == 2) vm = hf ? s3b : s3a;
                else               vm = hf ? s4b : s4a;
                mask_lds[sl * 8 + lane] = vm;   // lane = step*2 + half
            }
        }
        __syncthreads();

        // ---- phase 1.5: expand masks -> A-fragments (wave builds its tile) ----
        {
            int r   = lane & 15;                       // row within tile
            int sl  = tile_own * 4 + (r >> 2);         // site_local
            int stp = r & 3;
            const unsigned char* mb = (const unsigned char*)&mask_lds[sl * 8 + stp * 2];
            #pragma unroll
            for (int c = 0; c < 4; ++c) {
                unsigned int bt = mb[c * 4 + kg];      // 8 channels' bits
                u64 lo = lut[bt & 15], hi = lut[bt >> 4];
                uint4 fr;
                fr.x = (unsigned)lo; fr.y = (unsigned)(lo >> 32);
                fr.z = (unsigned)hi; fr.w = (unsigned)(hi >> 32);
                u.afrag[(tile_own * 4 + c) * 64 + lane] = fr;
            }
        }
        __syncthreads();

        // ---- phase 2: 8 M-tiles x wave's N-slice, split-bf16 MFMA + epilogue ----
        for (int j = 0; j < 8; ++j) {
            int tl = tbase + j;
            s8frag a0 = *(const s8frag*)&u.afrag[(tl * 4 + 0) * 64 + lane];
            s8frag a1 = *(const s8frag*)&u.afrag[(tl * 4 + 1) * 64 + lane];
            s8frag a2 = *(const s8frag*)&u.afrag[(tl * 4 + 2) * 64 + lane];
            s8frag a3 = *(const s8frag*)&u.afrag[(tl * 4 + 3) * 64 + lane];
            f4frag acc = { 0.f, 0.f, 0.f, 0.f };
            acc = __builtin_amdgcn_mfma_f32_16x16x32_bf16(a0, bhi[0], acc, 0, 0, 0);
            acc = __builtin_amdgcn_mfma_f32_16x16x32_bf16(a1, bhi[1], acc, 0, 0, 0);
            acc = __builtin_amdgcn_mfma_f32_16x16x32_bf16(a2, bhi[2], acc, 0, 0, 0);
            acc = __builtin_amdgcn_mfma_f32_16x16x32_bf16(a3, bhi[3], acc, 0, 0, 0);
            acc = __builtin_amdgcn_mfma_f32_16x16x32_bf16(a0, blo[0], acc, 0, 0, 0);
            acc = __builtin_amdgcn_mfma_f32_16x16x32_bf16(a1, blo[1], acc, 0, 0, 0);
            acc = __builtin_amdgcn_mfma_f32_16x16x32_bf16(a2, blo[2], acc, 0, 0, 0);
            acc = __builtin_amdgcn_mfma_f32_16x16x32_bf16(a3, blo[3], acc, 0, 0, 0);

            // epilogue: rows = site (lane>>4) x step (reg); col = channel ch
            float vv = 0.f;
            #pragma unroll
            for (int s = 0; s < 4; ++s) {
                float h2 = (acc[s] + b2c) * i2c + d2c;
                vv = vv + (h2 - vv) * 0.5f;
                bool sp = vv >= 0.5f;
                vv = sp ? 0.f : vv;
                facc += sp ? 1.f : 0.f;
            }
        }
        __syncthreads();   // before next group's mask/afrag overwrite
    }

    // ---- reduce facc: 4 row-groups per wave share a channel ----
    facc += __shfl_down(facc, 32);
    facc += __shfl_down(facc, 16);
    if (wave < 8) {
        if (lane < 16) red[slice * 16 + lane] = facc;
    }
    __syncthreads();
    if (wave >= 8 && lane < 16) {
        atomicAdd(&feat[b * H_ + ch], red[slice * 16 + lane] + facc);
    }
}

__global__ __launch_bounds__(128) void classifier_kernel(
    const float* __restrict__ feat,
    const float* __restrict__ wc,
    const float* __restrict__ bc,
    float* __restrict__ out) {
    __shared__ float fb[H_];
    int b = blockIdx.x, t = threadIdx.x;
    fb[t] = feat[b * H_ + t] * (1.0f / 32768.0f);   // 1/(S*T*V), exact pow2
    __syncthreads();
    if (t < NC_) {
        float s = 0.f;
        for (int h = 0; h < H_; ++h) s += fb[h] * wc[t * H_ + h];
        out[b * NC_ + t] = s + bc[t];
    }
}

extern "C" void kernel_launch(void* const* d_in, const int* in_sizes, int n_in,
                              void* d_out, int out_size, void* d_ws, size_t ws_size,
                              hipStream_t stream) {
    const float* x   = (const float*)d_in[0];
    const float* w1  = (const float*)d_in[1];
    const float* b1  = (const float*)d_in[2];
    const float* g1  = (const float*)d_in[3];
    const float* be1 = (const float*)d_in[4];
    const float* m1  = (const float*)d_in[5];
    const float* rv1 = (const float*)d_in[6];
    const float* w2  = (const float*)d_in[7];
    const float* b2  = (const float*)d_in[8];
    const float* g2  = (const float*)d_in[9];
    const float* be2 = (const float*)d_in[10];
    const float* m2  = (const float*)d_in[11];
    const float* rv2 = (const float*)d_in[12];
    const float* wc  = (const float*)d_in[13];
    const float* bc  = (const float*)d_in[14];
    float* feat = (float*)d_ws;
    float* out  = (float*)d_out;

    zero_feat_kernel<<<2, 1024, 0, stream>>>(feat);
    snn_main<<<1024, 1024, 0, stream>>>(x, w1, b1, g1, be1, m1, rv1,
                                        w2, b2, g2, be2, m2, rv2, feat);
    classifier_kernel<<<B_, 128, 0, stream>>>(feat, wc, bc, out);
}

// Round 5
// 145.698 us; speedup vs baseline: 1.0634x; 1.0634x over previous
//
#include <hip/hip_runtime.h>
#include <hip/hip_bf16.h>
#include <stdint.h>
#include <math.h>

#define B_ 16
#define T_ 512
#define V_ 16
#define H_ 128
#define NC_ 12

typedef float v2f __attribute__((ext_vector_type(2)));
typedef __attribute__((ext_vector_type(8))) short s8frag;   // 8 bf16 (4 VGPRs)
typedef __attribute__((ext_vector_type(4))) float f4frag;   // 4 fp32 acc
typedef unsigned long long u64;

// ws layout (bytes): W2H u16[16384] @0 (32KB) | W2L u16[16384] @32768 | feat f32[2048] @65536
#define WS_W2L_OFF  32768
#define WS_FEAT_OFF 65536

// ---- prep: split w2 into bf16 hi/lo ([n=ch][k=o] row-major, R4-verified frag order); zero feat ----
__global__ __launch_bounds__(256) void prep_kernel(const float* __restrict__ w2,
                                                   unsigned short* __restrict__ w2h,
                                                   unsigned short* __restrict__ w2l,
                                                   float* __restrict__ feat) {
    int i = blockIdx.x * 256 + threadIdx.x;
    if (i < H_ * H_) {
        float w = w2[i];
        __hip_bfloat16 hb = __float2bfloat16(w);
        float hf = __bfloat162float(hb);
        __hip_bfloat16 lb = __float2bfloat16(w - hf);
        w2h[i] = *(unsigned short*)&hb;
        w2l[i] = *(unsigned short*)&lb;
    }
    if (i < B_ * H_) feat[i] = 0.f;
}

__device__ __forceinline__ uint4 expand8(unsigned bt) {
    // byte -> 8 bf16 {0,1}: dword j = bits(2j, 2j+1)
    uint4 r;
    r.x = ((bt      & 1u) * 0x3F80u) | (((bt >> 1) & 1u) * 0x3F800000u);
    r.y = (((bt >> 2) & 1u) * 0x3F80u) | (((bt >> 3) & 1u) * 0x3F800000u);
    r.z = (((bt >> 4) & 1u) * 0x3F80u) | (((bt >> 5) & 1u) * 0x3F800000u);
    r.w = (((bt >> 6) & 1u) * 0x3F80u) | (((bt >> 7) & 1u) * 0x3F800000u);
    return r;
}

// Block = 4 waves (256 thr). Per round: wave w builds A-tile w (4 sites x 4 steps
// = 16 rows, K=128 channels) into LDS (fragment-order, conflict-free), and
// consumes the previous round's 4 tiles against its register-resident B
// (N-slices w*32..w*32+31, split bf16 hi/lo). One barrier per round.
#define ROUNDS 4
__global__ __launch_bounds__(256, 3) void snn_main(
    const float* __restrict__ x,
    const float* __restrict__ w1, const float* __restrict__ b1,
    const float* __restrict__ g1, const float* __restrict__ be1,
    const float* __restrict__ m1, const float* __restrict__ rv1,
    const unsigned short* __restrict__ w2h, const unsigned short* __restrict__ w2l,
    const float* __restrict__ b2,
    const float* __restrict__ g2, const float* __restrict__ be2,
    const float* __restrict__ m2, const float* __restrict__ rv2,
    float* __restrict__ feat)
{
    __shared__ uint4 afrag[2][4][4][64];   // [buf][tile][chunk][lane] — 32 KB
    __shared__ uint4 msk[4][16];           // [tile][row]: (mx lo,hi, my lo,hi) — 1 KB

    const int tid  = threadIdx.x;
    const int lane = tid & 63;
    const int wv   = tid >> 6;             // 0..3
    const int kg   = lane >> 4;            // k-group
    const int nl   = lane & 15;            // n / row-within-tile lane index
    const int bb   = blockIdx.x >> 7;      // batch
    const int sbase = (blockIdx.x & 127) * (ROUNDS * 16);   // site base within batch

    // ---- LIF1/BN1 per-lane constants (channel pair lane, lane+64) ----
    const int p = lane, q = lane + 64;
    v2f w0v = { w1[p*3+0], w1[q*3+0] };
    v2f w1v = { w1[p*3+1], w1[q*3+1] };
    v2f w2v = { w1[p*3+2], w1[q*3+2] };
    v2f b1v = { b1[p], b1[q] };
    float i1a = g1[p] * (float)(1.0 / sqrt((double)(rv1[p] + 1e-5f)));
    float i1b = g1[q] * (float)(1.0 / sqrt((double)(rv1[q] + 1e-5f)));
    v2f i1v = { i1a, i1b };
    v2f d1v = { be1[p] - m1[p] * i1a, be1[q] - m1[q] * i1b };

    // ---- BN2 constants for this wave's two N-slices ----
    const int ch0 = wv * 32 + nl;
    const int ch1 = ch0 + 16;
    float i2c0 = g2[ch0] * (float)(1.0 / sqrt((double)(rv2[ch0] + 1e-5f)));
    float d2c0 = be2[ch0] - m2[ch0] * i2c0;
    float b2c0 = b2[ch0];
    float i2c1 = g2[ch1] * (float)(1.0 / sqrt((double)(rv2[ch1] + 1e-5f)));
    float d2c1 = be2[ch1] - m2[ch1] * i2c1;
    float b2c1 = b2[ch1];

    // ---- register-resident B fragments: 2 slices x 4 k-chunks x (hi,lo) ----
    s8frag bh0[4], bl0[4], bh1[4], bl1[4];
    #pragma unroll
    for (int c = 0; c < 4; ++c) {
        int i0 = ch0 * H_ + c * 32 + kg * 8;
        int i1 = ch1 * H_ + c * 32 + kg * 8;
        bh0[c] = *(const s8frag*)&w2h[i0];
        bl0[c] = *(const s8frag*)&w2l[i0];
        bh1[c] = *(const s8frag*)&w2h[i1];
        bl1[c] = *(const s8frag*)&w2l[i1];
    }

    float facc0 = 0.f, facc1 = 0.f;

    #define CONSUME(BUF)                                                        \
        for (int tt = 0; tt < 4; ++tt) {                                        \
            s8frag a0 = *(const s8frag*)&afrag[BUF][tt][0][lane];               \
            s8frag a1 = *(const s8frag*)&afrag[BUF][tt][1][lane];               \
            s8frag a2 = *(const s8frag*)&afrag[BUF][tt][2][lane];               \
            s8frag a3 = *(const s8frag*)&afrag[BUF][tt][3][lane];               \
            f4frag acc0 = {0.f,0.f,0.f,0.f}, acc1 = {0.f,0.f,0.f,0.f};          \
            acc0 = __builtin_amdgcn_mfma_f32_16x16x32_bf16(a0, bh0[0], acc0, 0,0,0); \
            acc0 = __builtin_amdgcn_mfma_f32_16x16x32_bf16(a1, bh0[1], acc0, 0,0,0); \
            acc0 = __builtin_amdgcn_mfma_f32_16x16x32_bf16(a2, bh0[2], acc0, 0,0,0); \
            acc0 = __builtin_amdgcn_mfma_f32_16x16x32_bf16(a3, bh0[3], acc0, 0,0,0); \
            acc0 = __builtin_amdgcn_mfma_f32_16x16x32_bf16(a0, bl0[0], acc0, 0,0,0); \
            acc0 = __builtin_amdgcn_mfma_f32_16x16x32_bf16(a1, bl0[1], acc0, 0,0,0); \
            acc0 = __builtin_amdgcn_mfma_f32_16x16x32_bf16(a2, bl0[2], acc0, 0,0,0); \
            acc0 = __builtin_amdgcn_mfma_f32_16x16x32_bf16(a3, bl0[3], acc0, 0,0,0); \
            acc1 = __builtin_amdgcn_mfma_f32_16x16x32_bf16(a0, bh1[0], acc1, 0,0,0); \
            acc1 = __builtin_amdgcn_mfma_f32_16x16x32_bf16(a1, bh1[1], acc1, 0,0,0); \
            acc1 = __builtin_amdgcn_mfma_f32_16x16x32_bf16(a2, bh1[2], acc1, 0,0,0); \
            acc1 = __builtin_amdgcn_mfma_f32_16x16x32_bf16(a3, bh1[3], acc1, 0,0,0); \
            acc1 = __builtin_amdgcn_mfma_f32_16x16x32_bf16(a0, bl1[0], acc1, 0,0,0); \
            acc1 = __builtin_amdgcn_mfma_f32_16x16x32_bf16(a1, bl1[1], acc1, 0,0,0); \
            acc1 = __builtin_amdgcn_mfma_f32_16x16x32_bf16(a2, bl1[2], acc1, 0,0,0); \
            acc1 = __builtin_amdgcn_mfma_f32_16x16x32_bf16(a3, bl1[3], acc1, 0,0,0); \
            float v0 = 0.f, v1 = 0.f;                                           \
            _Pragma("unroll")                                                   \
            for (int s = 0; s < 4; ++s) {                                       \
                float h20 = (acc0[s] + b2c0) * i2c0 + d2c0;                     \
                float h21 = (acc1[s] + b2c1) * i2c1 + d2c1;                     \
                v0 = v0 + (h20 - v0) * 0.5f;                                    \
                v1 = v1 + (h21 - v1) * 0.5f;                                    \
                bool s0 = v0 >= 0.5f, s1 = v1 >= 0.5f;                          \
                v0 = s0 ? 0.f : v0;  v1 = s1 ? 0.f : v1;                        \
                facc0 += s0 ? 1.f : 0.f;  facc1 += s1 ? 1.f : 0.f;              \
            }                                                                   \
        }

    for (int r = 0; r < ROUNDS; ++r) {
        // ---- build tile wv of set r: 4 sites, masks -> msk -> A-frags ----
        #pragma unroll
        for (int i = 0; i < 4; ++i) {
            int site = sbase + r * 16 + wv * 4 + i;
            int t = site >> 4, v = site & 15;
            const float* xp = x + ((size_t)(bb * T_ + t) * 3) * V_ + v;
            float x0 = xp[0], x1 = xp[V_], x2 = xp[2 * V_];   // wave-uniform

            v2f h1 = ((x0 * w0v + x1 * w1v + x2 * w2v) + b1v) * i1v + d1v;
            // exact unreset trajectory (reference rounding; monotone for crossers)
            v2f v1t = h1 * 0.5f;
            v2f v2t = v1t + h1 * 0.25f;
            v2f v3t = v2t + (h1 - v2t) * 0.5f;
            v2f v4t = v3t + (h1 - v3t) * 0.5f;

            u64 t1a = __ballot(v1t.x >= 0.5f), t2a = __ballot(v2t.x >= 0.5f);
            u64 t3a = __ballot(v3t.x >= 0.5f), t4a = __ballot(v4t.x >= 0.5f);
            u64 t1b = __ballot(v1t.y >= 0.5f), t2b = __ballot(v2t.y >= 0.5f);
            u64 t3b = __ballot(v3t.y >= 0.5f), t4b = __ballot(v4t.y >= 0.5f);
            // per-step spike masks: s1=t1, s2=t2, s3=t1|(t3&~t2), s4=t2|(t4&~t3)
            u64 s3a = t1a | (t3a & ~t2a), s3b = t1b | (t3b & ~t2b);
            u64 s4a = t2a | (t4a & ~t3a), s4b = t2b | (t4b & ~t3b);

            u64 mx = (lane == 0) ? t1a : (lane == 1) ? t2a : (lane == 2) ? s3a : s4a;
            u64 my = (lane == 0) ? t1b : (lane == 1) ? t2b : (lane == 2) ? s3b : s4b;
            if (lane < 4) {
                uint4 mm;
                mm.x = (unsigned)mx; mm.y = (unsigned)(mx >> 32);
                mm.z = (unsigned)my; mm.w = (unsigned)(my >> 32);
                msk[wv][i * 4 + lane] = mm;   // row = site_local*4 + step
            }
        }
        {
            // expand row (lane&15) into this lane's A-frag bytes (conflict-free)
            uint4 mm = msk[wv][nl];
            u64 wx = (u64)mm.x | ((u64)mm.y << 32);
            u64 wy = (u64)mm.z | ((u64)mm.w << 32);
            int sh = kg << 3;
            int buf = r & 1;
            afrag[buf][wv][0][lane] = expand8((unsigned)(wx >> sh) & 0xFFu);
            afrag[buf][wv][1][lane] = expand8((unsigned)(wx >> (sh + 32)) & 0xFFu);
            afrag[buf][wv][2][lane] = expand8((unsigned)(wy >> sh) & 0xFFu);
            afrag[buf][wv][3][lane] = expand8((unsigned)(wy >> (sh + 32)) & 0xFFu);
        }
        // ---- consume previous set while this set's builds land ----
        if (r > 0) { int pb = (r - 1) & 1; CONSUME(pb); }
        __syncthreads();
    }
    { int pb = (ROUNDS - 1) & 1; CONSUME(pb); }
    #undef CONSUME

    // ---- reduce the 4 site-quads sharing each channel, then one atomic ----
    facc0 += __shfl_xor(facc0, 16); facc0 += __shfl_xor(facc0, 32);
    facc1 += __shfl_xor(facc1, 16); facc1 += __shfl_xor(facc1, 32);
    if (lane < 16) {
        atomicAdd(&feat[bb * H_ + ch0], facc0);
        atomicAdd(&feat[bb * H_ + ch1], facc1);
    }
}

__global__ __launch_bounds__(128) void classifier_kernel(
    const float* __restrict__ feat,
    const float* __restrict__ wc,
    const float* __restrict__ bc,
    float* __restrict__ out) {
    __shared__ float fb[H_];
    int b = blockIdx.x, t = threadIdx.x;
    fb[t] = feat[b * H_ + t] * (1.0f / 32768.0f);   // 1/(S*T*V), exact pow2
    __syncthreads();
    if (t < NC_) {
        float s = 0.f;
        for (int h = 0; h < H_; ++h) s += fb[h] * wc[t * H_ + h];
        out[b * NC_ + t] = s + bc[t];
    }
}

extern "C" void kernel_launch(void* const* d_in, const int* in_sizes, int n_in,
                              void* d_out, int out_size, void* d_ws, size_t ws_size,
                              hipStream_t stream) {
    const float* x   = (const float*)d_in[0];
    const float* w1  = (const float*)d_in[1];
    const float* b1  = (const float*)d_in[2];
    const float* g1  = (const float*)d_in[3];
    const float* be1 = (const float*)d_in[4];
    const float* m1  = (const float*)d_in[5];
    const float* rv1 = (const float*)d_in[6];
    const float* w2  = (const float*)d_in[7];
    const float* b2  = (const float*)d_in[8];
    const float* g2  = (const float*)d_in[9];
    const float* be2 = (const float*)d_in[10];
    const float* m2  = (const float*)d_in[11];
    const float* rv2 = (const float*)d_in[12];
    const float* wc  = (const float*)d_in[13];
    const float* bc  = (const float*)d_in[14];

    unsigned short* w2h = (unsigned short*)d_ws;
    unsigned short* w2l = (unsigned short*)((char*)d_ws + WS_W2L_OFF);
    float* feat = (float*)((char*)d_ws + WS_FEAT_OFF);
    float* out  = (float*)d_out;

    prep_kernel<<<64, 256, 0, stream>>>(w2, w2h, w2l, feat);
    snn_main<<<2048, 256, 0, stream>>>(x, w1, b1, g1, be1, m1, rv1,
                                       w2h, w2l, b2, g2, be2, m2, rv2, feat);
    classifier_kernel<<<B_, 128, 0, stream>>>(feat, wc, bc, out);
}